// Round 12
// baseline (147.865 us; speedup 1.0000x reference)
//
#include <hip/hip_runtime.h>

// MoE router, fp32-accurate via bf16-split MFMA (verified absmax 9.8e-4).
// x = token_inputs * jitter; logits = x @ w + b; softmax E=64; top-2 mask.
// Tokens = 32768, H = 2048, E = 64.
//
// R12: pure-TLP design. R9-R11 proved the compiler drains LDS-DMA before any
// ds_read (three schedules, all ~180us profiled, VALUBusy ~18%); per-wave
// ILP surgery failed five rounds running. So: NO LDS, NO barriers, NO gll in
// the main loop -- direct fragment-layout global loads (R5-verified math),
// and hide latency with WAVE COUNT: K-split 4 -> 8192 independent waves
// (16 k-steps each), 20-32 waves/CU. Per-wave serial chains are fine when
// 5-8 waves/SIMD interleave; total issue work is ~25us chip-wide, so the
// floor is the 512 MB stream (~85-100us at effective HBM+L3 BW).
// LDS only for the k-split logit reduction + verified epilogue.

#define H   2048
#define E   64

typedef __attribute__((ext_vector_type(8))) short bf16x8;
typedef __attribute__((ext_vector_type(4))) float f32x4;

__device__ inline ushort f2bf_rne(float f) {
    union { float f; unsigned u; } c; c.f = f;
    const unsigned r = (c.u + 0x7FFFu + ((c.u >> 16) & 1u)) >> 16;
    return (ushort)r;
}
__device__ inline float bf2f(ushort h) {
    union { unsigned u; float f; } c; c.u = ((unsigned)h) << 16;
    return c.f;
}

// ---- pre-kernel: pack w into fragment-linear hi/lo bf16 (verified) ----
// frag-pair (ks,n), ks=0..63 global k-step: hi at bp+(ks*4+n)*1024 (+lane*8),
// lo at +512. slot s of lane (g,c) holds w[ks*32 + g*8 + s][n*16 + c].
__global__ __launch_bounds__(256)
void wpack_kernel(const float* __restrict__ w, ushort* __restrict__ bp)
{
    const int t    = blockIdx.x * 256 + threadIdx.x;  // 0..16383
    const int lane = t & 63;
    const int n    = (t >> 6) & 3;
    const int ks   = t >> 8;                          // 0..63
    const int c    = lane & 15, g = lane >> 4;

    const float* src = w + (size_t)(ks * 32 + g * 8) * E + n * 16 + c;
    bf16x8 vh, vl;
#pragma unroll
    for (int s = 0; s < 8; ++s) {
        const float  v = src[(size_t)s * E];
        const ushort h = f2bf_rne(v);
        vh[s] = (short)h;
        vl[s] = (short)f2bf_rne(v - bf2f(h));
    }
    ushort* d = bp + ((size_t)(ks * 4 + n) * 2 * 64 + lane) * 8;
    *(bf16x8*)d         = vh;
    *(bf16x8*)(d + 512) = vl;
}

// ---- main kernel ----
__global__ __launch_bounds__(256, 4)
void router_kernel(const float* __restrict__ xg,
                   const float* __restrict__ jg,
                   const ushort* __restrict__ bp,
                   const float* __restrict__ bias,
                   float* __restrict__ out)
{
    // k-split partial logits: slab per wave, rows padded to 68 words
    __shared__ float lgx[4][16][68];   // 17.4 KB

    const int tid  = threadIdx.x;
    const int wv   = tid >> 6;         // k-quarter
    const int lane = tid & 63;
    const int ln   = lane & 15;        // token row / expert col
    const int g    = lane >> 4;        // k-group
    const size_t tokBase = (size_t)blockIdx.x * 16;

    // A-side: lane (ln,g) reads rows of token ln, k-slots g*8..g*8+8
    const float* xp = xg + (tokBase + ln) * (size_t)H + wv * 512 + g * 8;
    const float* jp = jg + (tokBase + ln) * (size_t)H + wv * 512 + g * 8;
    // B-side: global k-step for this wave = wv*16 + ks
    const ushort* bpw = bp + (size_t)(wv * 16) * 4096 + (size_t)lane * 8;

    f32x4 acc0 = (f32x4){0.f, 0.f, 0.f, 0.f};
    f32x4 acc1 = (f32x4){0.f, 0.f, 0.f, 0.f};
    f32x4 acc2 = (f32x4){0.f, 0.f, 0.f, 0.f};
    f32x4 acc3 = (f32x4){0.f, 0.f, 0.f, 0.f};

#pragma unroll 2
    for (int ks = 0; ks < 16; ++ks) {
        const float* xq = xp + ks * 32;
        const float* jq = jp + ks * 32;
        const float4 x0 = *(const float4*)(xq);
        const float4 x1 = *(const float4*)(xq + 4);
        const float4 j0 = *(const float4*)(jq);
        const float4 j1 = *(const float4*)(jq + 4);

        float pr[8];
        pr[0] = x0.x * j0.x; pr[1] = x0.y * j0.y;
        pr[2] = x0.z * j0.z; pr[3] = x0.w * j0.w;
        pr[4] = x1.x * j1.x; pr[5] = x1.y * j1.y;
        pr[6] = x1.z * j1.z; pr[7] = x1.w * j1.w;

        bf16x8 ah, al;
#pragma unroll
        for (int i = 0; i < 8; ++i) {
            const ushort h = f2bf_rne(pr[i]);
            ah[i] = (short)h;
            al[i] = (short)f2bf_rne(pr[i] - bf2f(h));
        }

        const ushort* bq = bpw + (size_t)ks * 4096;
        {
            const bf16x8 BH = *(const bf16x8*)(bq);
            const bf16x8 BL = *(const bf16x8*)(bq + 512);
            acc0 = __builtin_amdgcn_mfma_f32_16x16x32_bf16(ah, BH, acc0, 0, 0, 0);
            acc0 = __builtin_amdgcn_mfma_f32_16x16x32_bf16(al, BH, acc0, 0, 0, 0);
            acc0 = __builtin_amdgcn_mfma_f32_16x16x32_bf16(ah, BL, acc0, 0, 0, 0);
        }
        {
            const bf16x8 BH = *(const bf16x8*)(bq + 1024);
            const bf16x8 BL = *(const bf16x8*)(bq + 1536);
            acc1 = __builtin_amdgcn_mfma_f32_16x16x32_bf16(ah, BH, acc1, 0, 0, 0);
            acc1 = __builtin_amdgcn_mfma_f32_16x16x32_bf16(al, BH, acc1, 0, 0, 0);
            acc1 = __builtin_amdgcn_mfma_f32_16x16x32_bf16(ah, BL, acc1, 0, 0, 0);
        }
        {
            const bf16x8 BH = *(const bf16x8*)(bq + 2048);
            const bf16x8 BL = *(const bf16x8*)(bq + 2560);
            acc2 = __builtin_amdgcn_mfma_f32_16x16x32_bf16(ah, BH, acc2, 0, 0, 0);
            acc2 = __builtin_amdgcn_mfma_f32_16x16x32_bf16(al, BH, acc2, 0, 0, 0);
            acc2 = __builtin_amdgcn_mfma_f32_16x16x32_bf16(ah, BL, acc2, 0, 0, 0);
        }
        {
            const bf16x8 BH = *(const bf16x8*)(bq + 3072);
            const bf16x8 BL = *(const bf16x8*)(bq + 3584);
            acc3 = __builtin_amdgcn_mfma_f32_16x16x32_bf16(ah, BH, acc3, 0, 0, 0);
            acc3 = __builtin_amdgcn_mfma_f32_16x16x32_bf16(al, BH, acc3, 0, 0, 0);
            acc3 = __builtin_amdgcn_mfma_f32_16x16x32_bf16(ah, BL, acc3, 0, 0, 0);
        }
    }

    // ---- write k-split partials (C/D map: row=g*4+r -> token, col=ln) ----
#pragma unroll
    for (int r = 0; r < 4; ++r) {
        lgx[wv][g * 4 + r][     ln] = acc0[r];
        lgx[wv][g * 4 + r][16 + ln] = acc1[r];
        lgx[wv][g * 4 + r][32 + ln] = acc2[r];
        lgx[wv][g * 4 + r][48 + ln] = acc3[r];
    }
    __syncthreads();

    // ---- epilogue: 8 threads per token (threads 0..127), verified logic ----
    if (tid < 128) {
        const int t8 = tid >> 3;           // token 0..15
        const int q8 = tid & 7;            // expert octet
        const int eb = q8 * 8;

        float l[8];
        {
            const float4 a0 = *(const float4*)&lgx[0][t8][eb];
            const float4 a1 = *(const float4*)&lgx[1][t8][eb];
            const float4 a2 = *(const float4*)&lgx[2][t8][eb];
            const float4 a3 = *(const float4*)&lgx[3][t8][eb];
            const float4 b0 = *(const float4*)&lgx[0][t8][eb + 4];
            const float4 b1 = *(const float4*)&lgx[1][t8][eb + 4];
            const float4 b2 = *(const float4*)&lgx[2][t8][eb + 4];
            const float4 b3 = *(const float4*)&lgx[3][t8][eb + 4];
            const float4 bb0 = *(const float4*)(bias + eb);
            const float4 bb1 = *(const float4*)(bias + eb + 4);
            l[0] = a0.x + a1.x + a2.x + a3.x + bb0.x;
            l[1] = a0.y + a1.y + a2.y + a3.y + bb0.y;
            l[2] = a0.z + a1.z + a2.z + a3.z + bb0.z;
            l[3] = a0.w + a1.w + a2.w + a3.w + bb0.w;
            l[4] = b0.x + b1.x + b2.x + b3.x + bb1.x;
            l[5] = b0.y + b1.y + b2.y + b3.y + bb1.y;
            l[6] = b0.z + b1.z + b2.z + b3.z + bb1.z;
            l[7] = b0.w + b1.w + b2.w + b3.w + bb1.w;
        }

        // local top-2 (strict '>' ascending keeps lowest index on ties)
        float p1 = l[0]; int i1 = eb;
        float p2 = -3.0e38f; int i2 = eb;
#pragma unroll
        for (int i = 1; i < 8; ++i) {
            const int e = eb + i;
            if (l[i] > p1)      { p2 = p1; i2 = i1; p1 = l[i]; i1 = e; }
            else if (l[i] > p2) { p2 = l[i]; i2 = e; }
        }

        // butterfly merge across the token's 8 threads
#pragma unroll
        for (int m = 1; m <= 4; m <<= 1) {
            const float q1 = __shfl_xor(p1, m, 8);
            const int   k1 = __shfl_xor(i1, m, 8);
            const float q2 = __shfl_xor(p2, m, 8);
            const int   k2 = __shfl_xor(i2, m, 8);
            const bool  bw = (q1 > p1) || (q1 == p1 && k1 < i1);
            const float f1 = bw ? q1 : p1;  const int fi1 = bw ? k1 : i1;
            const float lo = bw ? p1 : q1;  const int loi = bw ? i1 : k1;
            const float sn = bw ? q2 : p2;  const int sni = bw ? k2 : i2;
            const bool  rw = (lo > sn) || (lo == sn && loi < sni);
            p2 = rw ? lo : sn;  i2 = rw ? loi : sni;
            p1 = f1;            i1 = fi1;
        }

        float d = 0.f;
#pragma unroll
        for (int i = 0; i < 8; ++i) d += __expf(l[i] - p1);
#pragma unroll
        for (int m = 1; m <= 4; m <<= 1) d += __shfl_xor(d, m, 8);

        const float inv = 1.f / d;                 // top-1 prob
        const float w2  = __expf(p2 - p1) * inv;   // top-2 prob

        float* op = out + (tokBase + t8) * (size_t)E + eb;
        float4 v0, v1;
        v0.x = (eb + 0 == i1) ? inv : (eb + 0 == i2) ? w2 : 0.f;
        v0.y = (eb + 1 == i1) ? inv : (eb + 1 == i2) ? w2 : 0.f;
        v0.z = (eb + 2 == i1) ? inv : (eb + 2 == i2) ? w2 : 0.f;
        v0.w = (eb + 3 == i1) ? inv : (eb + 3 == i2) ? w2 : 0.f;
        v1.x = (eb + 4 == i1) ? inv : (eb + 4 == i2) ? w2 : 0.f;
        v1.y = (eb + 5 == i1) ? inv : (eb + 5 == i2) ? w2 : 0.f;
        v1.z = (eb + 6 == i1) ? inv : (eb + 6 == i2) ? w2 : 0.f;
        v1.w = (eb + 7 == i1) ? inv : (eb + 7 == i2) ? w2 : 0.f;
        *(float4*)op       = v0;
        *(float4*)(op + 4) = v1;
    }
}

extern "C" void kernel_launch(void* const* d_in, const int* in_sizes, int n_in,
                              void* d_out, int out_size, void* d_ws, size_t ws_size,
                              hipStream_t stream)
{
    const float* x   = (const float*)d_in[0];
    const float* jit = (const float*)d_in[1];
    const float* w   = (const float*)d_in[2];
    const float* b   = (const float*)d_in[3];
    float*       out = (float*)d_out;

    ushort* bpack = (ushort*)d_ws;   // 512 frag-pairs x 1 KB = 512 KB

    hipLaunchKernelGGL(wpack_kernel, dim3(64), dim3(256), 0, stream, w, bpack);

    const int n_tok = in_sizes[0] / H;   // 32768
    dim3 grid(n_tok / 16), block(256);
    hipLaunchKernelGGL(router_kernel, grid, block, 0, stream,
                       x, jit, bpack, b, out);
}